// Round 4
// baseline (636.874 us; speedup 1.0000x reference)
//
#include <hip/hip_runtime.h>
#include <cmath>

#define HIDC 48

// ---------------------------------------------------------------------------
// block-wide mean/var over NPIX values spread across 1024 threads.
// red must have >= 34 floats of shared storage.
// ---------------------------------------------------------------------------
__device__ __forceinline__ void block_meanvar1024(float s, float s2, float* red,
                                                  float cntinv, float& m, float& v)
{
#pragma unroll
    for (int off = 32; off > 0; off >>= 1) {
        s  += __shfl_down(s, off);
        s2 += __shfl_down(s2, off);
    }
    int wid  = threadIdx.x >> 6;   // 0..15
    int lane = threadIdx.x & 63;
    if (lane == 0) { red[wid] = s; red[16 + wid] = s2; }
    __syncthreads();
    if (threadIdx.x == 0) {
        float ts = 0.f, ts2 = 0.f;
#pragma unroll
        for (int i = 0; i < 16; ++i) { ts += red[i]; ts2 += red[16 + i]; }
        red[32] = ts; red[33] = ts2;
    }
    __syncthreads();
    float mean = red[32] * cntinv;
    m = mean;
    v = red[33] * cntinv - mean * mean;
    __syncthreads();
}

// ---------------------------------------------------------------------------
// Pure conv3x3(SAME, zero-pad) + bias. Block of 256 threads computes a tile
// of ROWS x W pixels for COG consecutive couts (LDS tile amortized over COG).
// Grid: (COUT/COG, H/ROWS, N). Double-buffered LDS, one barrier per stage.
// ---------------------------------------------------------------------------
template <int H, int W, int ROWS, int COG, int CPS>
__global__ __launch_bounds__(256) void conv_tile(
    const float* __restrict__ in,    // (N, 48, H, W)
    const float* __restrict__ wgt,   // (COUT, 48, 3, 3)
    const float* __restrict__ bias,  // (COUT)
    float* __restrict__ out)         // (N, COUT, H, W)
{
    constexpr int NPIX  = H * W;
    constexpr int PW    = W + 2;
    constexpr int TILER = ROWS + 2;
    constexpr int CHSZ  = TILER * PW;
    constexpr int LSZ   = CPS * CHSZ;
    constexpr int TX    = (W >= 64) ? 64 : 32;
    constexpr int TYN   = 256 / TX;
    constexpr int RPT   = ROWS / TYN;      // rows per thread (column strip)
    constexpr int NS    = 48 / CPS;

    __shared__ float plane[2][LSZ];

    const int t    = threadIdx.x;
    const int cg   = blockIdx.x;
    const int rt   = blockIdx.y;
    const int n    = blockIdx.z;
    const int COUT = gridDim.x * COG;
    const int co0  = cg * COG;
    const int tx   = t % TX;
    const int ty   = t / TX;
    const int r0   = rt * ROWS;            // first output row of this tile

    float acc[COG][RPT];
#pragma unroll
    for (int co = 0; co < COG; ++co)
#pragma unroll
        for (int r = 0; r < RPT; ++r) acc[co][r] = 0.f;

    const float* inb = in + (size_t)n * 48 * NPIX;

    int buf = 0;
    for (int s = 0; s < NS; ++s) {
        const float* cb = inb + (size_t)s * CPS * NPIX;
        for (int i = t; i < LSZ; i += 256) {
            int ch  = i / CHSZ;
            int rem = i % CHSZ;
            int ly  = rem / PW, lx = rem % PW;
            int gy  = r0 + ly - 1, gx = lx - 1;
            float v = 0.f;
            if (gy >= 0 && gy < H && gx >= 0 && gx < W)
                v = cb[(size_t)ch * NPIX + gy * W + gx];
            plane[buf][i] = v;
        }
        __syncthreads();

#pragma unroll
        for (int c = 0; c < CPS; ++c) {
            const float* P = &plane[buf][c * CHSZ];
            float wv[COG][9];
#pragma unroll
            for (int co = 0; co < COG; ++co)
#pragma unroll
                for (int k = 0; k < 9; ++k)
                    wv[co][k] = wgt[((size_t)(co0 + co) * 48 + s * CPS + c) * 9 + k];
#pragma unroll
            for (int dx = 0; dx < 3; ++dx) {
                float v[RPT + 2];
#pragma unroll
                for (int j = 0; j < RPT + 2; ++j)
                    v[j] = P[(ty * RPT + j) * PW + tx + dx];
#pragma unroll
                for (int co = 0; co < COG; ++co)
#pragma unroll
                    for (int r = 0; r < RPT; ++r)
                        acc[co][r] += v[r]     * wv[co][dx]
                                    + v[r + 1] * wv[co][dx + 3]
                                    + v[r + 2] * wv[co][dx + 6];
            }
        }
        buf ^= 1;
        // single barrier per stage: stage s+1 writes the buffer last read at
        // s-1; every thread passed the stage-s barrier only after finishing
        // its s-1 compute, so no hazard.
    }

#pragma unroll
    for (int co = 0; co < COG; ++co) {
        const float bv = bias[co0 + co];
        const size_t ob = ((size_t)n * COUT + co0 + co) * NPIX;
#pragma unroll
        for (int r = 0; r < RPT; ++r)
            out[ob + (size_t)(r0 + ty * RPT + r) * W + tx] = acc[co][r] + bv;
    }
}

// ---------------------------------------------------------------------------
// Per-plane epilogue: inorm, prelu [, inorm, +residual].
// One block of 1024 threads per (co, n) plane; data stays in registers.
//   MODE 0: inorm, prelu, inorm, +res   MODE 1: inorm, prelu
// ---------------------------------------------------------------------------
template <int NPIX, int MODE>
__global__ __launch_bounds__(1024) void norm_block(
    const float* __restrict__ conv,  // (N,48,NPIX) conv+bias output
    const float* __restrict__ res,   // residual (N,48,NPIX), null in MODE 1
    const float* __restrict__ aptr,  // prelu slope scalar
    float* __restrict__ out)         // (N,48,NPIX)
{
    constexpr int TY = NPIX / 1024;
    __shared__ float red[34];
    const int t  = threadIdx.x;
    const int co = blockIdx.x;
    const int n  = blockIdx.y;
    const size_t base = ((size_t)n * 48 + co) * NPIX;
    constexpr float cntinv = 1.f / (float)NPIX;

    float acc[TY];
#pragma unroll
    for (int r = 0; r < TY; ++r) acc[r] = conv[base + t + r * 1024];

    {
        float s = 0.f, s2 = 0.f;
#pragma unroll
        for (int r = 0; r < TY; ++r) { s += acc[r]; s2 += acc[r] * acc[r]; }
        float m, v;
        block_meanvar1024(s, s2, red, cntinv, m, v);
        float rr = rsqrtf(v + 1e-5f);
#pragma unroll
        for (int r = 0; r < TY; ++r) acc[r] = (acc[r] - m) * rr;
    }

    const float a = aptr[0];
#pragma unroll
    for (int r = 0; r < TY; ++r) acc[r] = acc[r] >= 0.f ? acc[r] : a * acc[r];

    if (MODE == 0) {
        float s = 0.f, s2 = 0.f;
#pragma unroll
        for (int r = 0; r < TY; ++r) { s += acc[r]; s2 += acc[r] * acc[r]; }
        float m, v;
        block_meanvar1024(s, s2, red, cntinv, m, v);
        float rr = rsqrtf(v + 1e-5f);
#pragma unroll
        for (int r = 0; r < TY; ++r)
            acc[r] = (acc[r] - m) * rr + res[base + t + r * 1024];
    }

#pragma unroll
    for (int r = 0; r < TY; ++r) out[base + t + r * 1024] = acc[r];
}

// ---------------------------------------------------------------------------
// x1 = x_[:, :, ::4, ::4]   (4,48,256,256) -> (4,48,64,64)
// ---------------------------------------------------------------------------
__global__ __launch_bounds__(256) void downsample4(const float* __restrict__ xin,
                                                   float* __restrict__ o)
{
    int idx = blockIdx.x * 256 + threadIdx.x;        // 786432
    int j = idx & 63;
    int i = (idx >> 6) & 63;
    int nc = idx >> 12;
    o[idx] = xin[((size_t)nc * 256 + i * 4) * 256 + j * 4];
}

// ---------------------------------------------------------------------------
// 2x2 max pool  (4,48,64,64) -> (4,48,32,32)
// ---------------------------------------------------------------------------
__global__ __launch_bounds__(256) void maxpool2k(const float* __restrict__ a,
                                                 float* __restrict__ o)
{
    int idx = blockIdx.x * 256 + threadIdx.x;        // 196608
    int j = idx & 31;
    int i = (idx >> 5) & 31;
    int nc = idx >> 10;
    const float* p = a + ((size_t)nc * 64 + i * 2) * 64 + j * 2;
    o[idx] = fmaxf(fmaxf(p[0], p[1]), fmaxf(p[64], p[65]));
}

// ---------------------------------------------------------------------------
// Fused: bilinear 8x upsample of skernel (4,9,32,32), per-pixel softmax over
// the 9 taps, 3x3 reflect-padded apply to x (4,48,256,256).
// Grid (16, 256): x = n*4+cgroup (12 channels), y = output row h.
// ---------------------------------------------------------------------------
__global__ __launch_bounds__(256) void apply_fused(const float* __restrict__ x,
                                                   const float* __restrict__ sk,
                                                   float* __restrict__ out)
{
    __shared__ float skr[9][2][32];
    __shared__ float kvs[256 * 9];   // [w][9]
    const int bx = blockIdx.x;
    const int n  = bx >> 2;
    const int cg = bx & 3;
    const int h  = blockIdx.y;
    const int t  = threadIdx.x;

    float fs = (float)h * 31.0f / 255.0f;
    int r0 = (int)fs;
    float fh = fs - (float)r0;
    int r1 = min(r0 + 1, 31);

    for (int i = t; i < 576; i += 256) {
        int p = i >> 6, rsel = (i >> 5) & 1, c = i & 31;
        int rr = rsel ? r1 : r0;
        skr[p][rsel][c] = sk[((n * 9 + p) * 32 + rr) * 32 + c];
    }
    __syncthreads();

    {
        float fcs = (float)t * 31.0f / 255.0f;
        int c0 = (int)fcs;
        float fx = fcs - (float)c0;
        int c1 = min(c0 + 1, 31);
        float kv[9];
        float mx = -1e30f;
#pragma unroll
        for (int p = 0; p < 9; ++p) {
            float v0 = skr[p][0][c0] * (1.f - fx) + skr[p][0][c1] * fx;
            float v1 = skr[p][1][c0] * (1.f - fx) + skr[p][1][c1] * fx;
            float v  = v0 * (1.f - fh) + v1 * fh;
            kv[p] = v;
            mx = fmaxf(mx, v);
        }
        float ss = 0.f;
#pragma unroll
        for (int p = 0; p < 9; ++p) { kv[p] = __expf(kv[p] - mx); ss += kv[p]; }
        float inv = 1.f / ss;
#pragma unroll
        for (int p = 0; p < 9; ++p) kvs[t * 9 + p] = kv[p] * inv;
    }
    __syncthreads();

    const int wq = t & 63;
    const int cl = t >> 6;
    const int w4 = wq * 4;

    float kv[4][9];
#pragma unroll
    for (int j = 0; j < 4; ++j)
#pragma unroll
        for (int p = 0; p < 9; ++p) kv[j][p] = kvs[(w4 + j) * 9 + p];

    const int hm  = (h == 0) ? 1 : h - 1;
    const int hp  = (h == 255) ? 254 : h + 1;
    const int xle = (w4 == 0) ? 1 : w4 - 1;
    const int xre = (w4 == 252) ? 254 : w4 + 4;

    const int c0ch = cg * 12 + cl * 3;
    const float* xb = x + ((size_t)n * HIDC + c0ch) * 65536;
    float* ob = out + ((size_t)n * HIDC + c0ch) * 65536;

    for (int c = 0; c < 3; ++c) {
        const float* xp = xb + (size_t)c * 65536;
        const float* rm = xp + hm * 256;
        const float* rc = xp + h * 256;
        const float* rp = xp + hp * 256;
        float4 fm = *(const float4*)(rm + w4);
        float4 fc = *(const float4*)(rc + w4);
        float4 fp = *(const float4*)(rp + w4);
        float vm[6] = { rm[xle], fm.x, fm.y, fm.z, fm.w, rm[xre] };
        float vc[6] = { rc[xle], fc.x, fc.y, fc.z, fc.w, rc[xre] };
        float vp[6] = { rp[xle], fp.x, fp.y, fp.z, fp.w, rp[xre] };
        float4 o;
        float* op = &o.x;
#pragma unroll
        for (int j = 0; j < 4; ++j) {
            op[j] = kv[j][0] * vm[j] + kv[j][1] * vm[j + 1] + kv[j][2] * vm[j + 2]
                  + kv[j][3] * vc[j] + kv[j][4] * vc[j + 1] + kv[j][5] * vc[j + 2]
                  + kv[j][6] * vp[j] + kv[j][7] * vp[j + 1] + kv[j][8] * vp[j + 2];
        }
        *(float4*)(ob + (size_t)c * 65536 + h * 256 + w4) = o;
    }
}

extern "C" void kernel_launch(void* const* d_in, const int* in_sizes, int n_in,
                              void* d_out, int out_size, void* d_ws, size_t ws_size,
                              hipStream_t stream)
{
    const float* x       = (const float*)d_in[0];
    const float* x_      = (const float*)d_in[1];
    const float* pre1_w  = (const float*)d_in[2];
    const float* pre1_b  = (const float*)d_in[3];
    const float* pre1_a  = (const float*)d_in[4];
    const float* pre2_w  = (const float*)d_in[5];
    const float* pre2_b  = (const float*)d_in[6];
    const float* pre2_a  = (const float*)d_in[7];
    const float* prek_w1 = (const float*)d_in[8];
    const float* prek_b1 = (const float*)d_in[9];
    const float* prek_a  = (const float*)d_in[10];
    const float* prek_w2 = (const float*)d_in[11];
    const float* prek_b2 = (const float*)d_in[12];
    float* out = (float*)d_out;

    // workspace layout (floats). A is reused for the 32x32 stage buffers
    // once the 64x64 phase no longer needs it.
    float* A   = (float*)d_ws;          // (4,48,64,64) = 786432
    float* B   = A + 786432;            // (4,48,64,64)
    float* RAW = B + 786432;            // (4,48,64,64) raw conv out
    float* C   = A;                     // (4,48,32,32) = 196608  (A dead by then)
    float* D   = A + 196608;            // (4,48,32,32)
    float* R2  = A + 393216;            // (4,48,32,32) raw conv out
    float* SK  = A + 589824;            // (4,9,32,32)  = 36864

    const int W1 = 48 * 48 * 9;

    downsample4<<<3072, 256, 0, stream>>>(x_, A);

    // ---- 3 basic blocks @ 64x64 ----
    conv_tile<64, 64, 8, 4, 4><<<dim3(12, 8, 4), 256, 0, stream>>>(A, pre1_w, pre1_b, RAW);
    norm_block<4096, 0><<<dim3(48, 4), 1024, 0, stream>>>(RAW, A, pre1_a, B);
    conv_tile<64, 64, 8, 4, 4><<<dim3(12, 8, 4), 256, 0, stream>>>(B, pre1_w + W1, pre1_b + 48, RAW);
    norm_block<4096, 0><<<dim3(48, 4), 1024, 0, stream>>>(RAW, B, pre1_a + 1, A);
    conv_tile<64, 64, 8, 4, 4><<<dim3(12, 8, 4), 256, 0, stream>>>(A, pre1_w + 2 * W1, pre1_b + 96, RAW);
    norm_block<4096, 0><<<dim3(48, 4), 1024, 0, stream>>>(RAW, A, pre1_a + 2, B);

    maxpool2k<<<768, 256, 0, stream>>>(B, C);

    // ---- 3 basic blocks @ 32x32 ----
    conv_tile<32, 32, 8, 4, 8><<<dim3(12, 4, 4), 256, 0, stream>>>(C, pre2_w, pre2_b, R2);
    norm_block<1024, 0><<<dim3(48, 4), 1024, 0, stream>>>(R2, C, pre2_a, D);
    conv_tile<32, 32, 8, 4, 8><<<dim3(12, 4, 4), 256, 0, stream>>>(D, pre2_w + W1, pre2_b + 48, R2);
    norm_block<1024, 0><<<dim3(48, 4), 1024, 0, stream>>>(R2, D, pre2_a + 1, C);
    conv_tile<32, 32, 8, 4, 8><<<dim3(12, 4, 4), 256, 0, stream>>>(C, pre2_w + 2 * W1, pre2_b + 96, R2);
    norm_block<1024, 0><<<dim3(48, 4), 1024, 0, stream>>>(R2, C, pre2_a + 2, D);

    // ---- kernel-prediction heads ----
    conv_tile<32, 32, 8, 4, 8><<<dim3(12, 4, 4), 256, 0, stream>>>(D, prek_w1, prek_b1, R2);
    norm_block<1024, 1><<<dim3(48, 4), 1024, 0, stream>>>(R2, nullptr, prek_a, C);
    conv_tile<32, 32, 8, 3, 8><<<dim3(3, 4, 4), 256, 0, stream>>>(C, prek_w2, prek_b2, SK);

    apply_fused<<<dim3(16, 256), 256, 0, stream>>>(x, SK, out);
}

// Round 5
// 393.453 us; speedup vs baseline: 1.6187x; 1.6187x over previous
//
#include <hip/hip_runtime.h>
#include <cmath>

#define HIDC 48

// ---------------------------------------------------------------------------
// block-wide mean/var over NPIX values spread across 1024 threads.
// ---------------------------------------------------------------------------
__device__ __forceinline__ void block_meanvar1024(float s, float s2, float* red,
                                                  float cntinv, float& m, float& v)
{
#pragma unroll
    for (int off = 32; off > 0; off >>= 1) {
        s  += __shfl_down(s, off);
        s2 += __shfl_down(s2, off);
    }
    int wid  = threadIdx.x >> 6;   // 0..15
    int lane = threadIdx.x & 63;
    if (lane == 0) { red[wid] = s; red[16 + wid] = s2; }
    __syncthreads();
    if (threadIdx.x == 0) {
        float ts = 0.f, ts2 = 0.f;
#pragma unroll
        for (int i = 0; i < 16; ++i) { ts += red[i]; ts2 += red[16 + i]; }
        red[32] = ts; red[33] = ts2;
    }
    __syncthreads();
    float mean = red[32] * cntinv;
    m = mean;
    v = red[33] * cntinv - mean * mean;
    __syncthreads();
}

// ---------------------------------------------------------------------------
// Pure conv3x3(SAME, zero-pad) + bias.
// 256 threads; each thread computes PXT horizontally-consecutive pixels of
// one row for COG consecutive couts. Tile = ROWS x W. Grid:
// (COUT/COG, H/ROWS, N). Small per-thread work => many waves (12/CU at
// 64x64) for latency hiding; register prefetch of stage s+1's global data
// during stage s compute; double-buffered LDS with ONE barrier per stage
// (stage s+1 writes the buffer read at s-1; every thread's s-1 reads precede
// its barrier_s arrival, and writes follow barrier_s departure => safe).
// ---------------------------------------------------------------------------
template <int H, int W, int ROWS, int COG, int CPS, int PXT>
__global__ __launch_bounds__(256) void conv_tile(
    const float* __restrict__ in,    // (N, 48, H, W)
    const float* __restrict__ wgt,   // (COUT, 48, 3, 3)
    const float* __restrict__ bias,  // (COUT)
    float* __restrict__ out)         // (N, COUT, H, W)
{
    constexpr int NPIX = H * W;
    constexpr int PW   = W + 2;
    constexpr int CHSZ = (ROWS + 2) * PW;
    constexpr int LSZ  = CPS * CHSZ;
    constexpr int TXN  = W / PXT;          // threads per row
    constexpr int NS   = 48 / CPS;
    constexpr int LPT  = (LSZ + 255) / 256;

    static_assert(ROWS * TXN == 256, "block must be 256 threads");

    __shared__ float plane[2][LSZ];

    const int t    = threadIdx.x;
    const int cg   = blockIdx.x;
    const int rt   = blockIdx.y;
    const int n    = blockIdx.z;
    const int COUT = gridDim.x * COG;
    const int co0  = cg * COG;
    const int tx   = t % TXN;
    const int ty   = t / TXN;              // row within tile
    const int x0   = tx * PXT;
    const int r0   = rt * ROWS;

    float acc[COG][PXT];
#pragma unroll
    for (int co = 0; co < COG; ++co)
#pragma unroll
        for (int p = 0; p < PXT; ++p) acc[co][p] = 0.f;

    const float* inb = in + (size_t)n * 48 * NPIX;

    // prefetch stage 0
    float pref[LPT];
#pragma unroll
    for (int k = 0; k < LPT; ++k) {
        int i = t + k * 256;
        float v = 0.f;
        if (i < LSZ) {
            int ch  = i / CHSZ;
            int rem = i % CHSZ;
            int ly  = rem / PW, lx = rem % PW;
            int gy  = r0 + ly - 1, gx = lx - 1;
            if (gy >= 0 && gy < H && gx >= 0 && gx < W)
                v = inb[(size_t)ch * NPIX + gy * W + gx];
        }
        pref[k] = v;
    }

    int buf = 0;
    for (int s = 0; s < NS; ++s) {
        float cur[LPT];
#pragma unroll
        for (int k = 0; k < LPT; ++k) cur[k] = pref[k];
        if (s + 1 < NS) {
            const float* nb = inb + (size_t)(s + 1) * CPS * NPIX;
#pragma unroll
            for (int k = 0; k < LPT; ++k) {
                int i = t + k * 256;
                float v = 0.f;
                if (i < LSZ) {
                    int ch  = i / CHSZ;
                    int rem = i % CHSZ;
                    int ly  = rem / PW, lx = rem % PW;
                    int gy  = r0 + ly - 1, gx = lx - 1;
                    if (gy >= 0 && gy < H && gx >= 0 && gx < W)
                        v = nb[(size_t)ch * NPIX + gy * W + gx];
                }
                pref[k] = v;
            }
        }
#pragma unroll
        for (int k = 0; k < LPT; ++k) {
            int i = t + k * 256;
            if (i < LSZ) plane[buf][i] = cur[k];
        }
        __syncthreads();

#pragma unroll
        for (int c = 0; c < CPS; ++c) {
            const float* P = &plane[buf][c * CHSZ];
            float wv[COG][9];
#pragma unroll
            for (int co = 0; co < COG; ++co)
#pragma unroll
                for (int k = 0; k < 9; ++k)
                    wv[co][k] = wgt[((size_t)(co0 + co) * 48 + s * CPS + c) * 9 + k];
            // window rows ty..ty+2 (LDS rows), cols x0..x0+PXT+1
            float vr[3][PXT + 2];
#pragma unroll
            for (int r = 0; r < 3; ++r)
#pragma unroll
                for (int j = 0; j < PXT + 2; ++j)
                    vr[r][j] = P[(ty + r) * PW + x0 + j];
#pragma unroll
            for (int co = 0; co < COG; ++co)
#pragma unroll
                for (int p = 0; p < PXT; ++p) {
                    float s0 = vr[0][p]     * wv[co][0] + vr[0][p + 1] * wv[co][1]
                             + vr[0][p + 2] * wv[co][2] + vr[1][p]     * wv[co][3]
                             + vr[1][p + 1] * wv[co][4] + vr[1][p + 2] * wv[co][5]
                             + vr[2][p]     * wv[co][6] + vr[2][p + 1] * wv[co][7]
                             + vr[2][p + 2] * wv[co][8];
                    acc[co][p] += s0;
                }
        }
        buf ^= 1;
    }

#pragma unroll
    for (int co = 0; co < COG; ++co) {
        const float bv = bias[co0 + co];
        float* op = out + (((size_t)n * COUT + co0 + co) * H + r0 + ty) * W + x0;
        if (PXT == 2) {
            float2 o2 = make_float2(acc[co][0] + bv, acc[co][PXT - 1] + bv);
            *(float2*)op = o2;
        } else {
#pragma unroll
            for (int p = 0; p < PXT; ++p) op[p] = acc[co][p] + bv;
        }
    }
}

// ---------------------------------------------------------------------------
// Per-plane epilogue: inorm, prelu [, inorm, +residual].
//   MODE 0: inorm, prelu, inorm, +res   MODE 1: inorm, prelu
// ---------------------------------------------------------------------------
template <int NPIX, int MODE>
__global__ __launch_bounds__(1024) void norm_block(
    const float* __restrict__ conv,
    const float* __restrict__ res,
    const float* __restrict__ aptr,
    float* __restrict__ out)
{
    constexpr int TY = NPIX / 1024;
    __shared__ float red[34];
    const int t  = threadIdx.x;
    const int co = blockIdx.x;
    const int n  = blockIdx.y;
    const size_t base = ((size_t)n * 48 + co) * NPIX;
    constexpr float cntinv = 1.f / (float)NPIX;

    float acc[TY];
#pragma unroll
    for (int r = 0; r < TY; ++r) acc[r] = conv[base + t + r * 1024];

    {
        float s = 0.f, s2 = 0.f;
#pragma unroll
        for (int r = 0; r < TY; ++r) { s += acc[r]; s2 += acc[r] * acc[r]; }
        float m, v;
        block_meanvar1024(s, s2, red, cntinv, m, v);
        float rr = rsqrtf(v + 1e-5f);
#pragma unroll
        for (int r = 0; r < TY; ++r) acc[r] = (acc[r] - m) * rr;
    }

    const float a = aptr[0];
#pragma unroll
    for (int r = 0; r < TY; ++r) acc[r] = acc[r] >= 0.f ? acc[r] : a * acc[r];

    if (MODE == 0) {
        float s = 0.f, s2 = 0.f;
#pragma unroll
        for (int r = 0; r < TY; ++r) { s += acc[r]; s2 += acc[r] * acc[r]; }
        float m, v;
        block_meanvar1024(s, s2, red, cntinv, m, v);
        float rr = rsqrtf(v + 1e-5f);
#pragma unroll
        for (int r = 0; r < TY; ++r)
            acc[r] = (acc[r] - m) * rr + res[base + t + r * 1024];
    }

#pragma unroll
    for (int r = 0; r < TY; ++r) out[base + t + r * 1024] = acc[r];
}

// ---------------------------------------------------------------------------
__global__ __launch_bounds__(256) void downsample4(const float* __restrict__ xin,
                                                   float* __restrict__ o)
{
    int idx = blockIdx.x * 256 + threadIdx.x;        // 786432
    int j = idx & 63;
    int i = (idx >> 6) & 63;
    int nc = idx >> 12;
    o[idx] = xin[((size_t)nc * 256 + i * 4) * 256 + j * 4];
}

// ---------------------------------------------------------------------------
__global__ __launch_bounds__(256) void maxpool2k(const float* __restrict__ a,
                                                 float* __restrict__ o)
{
    int idx = blockIdx.x * 256 + threadIdx.x;        // 196608
    int j = idx & 31;
    int i = (idx >> 5) & 31;
    int nc = idx >> 10;
    const float* p = a + ((size_t)nc * 64 + i * 2) * 64 + j * 2;
    o[idx] = fmaxf(fmaxf(p[0], p[1]), fmaxf(p[64], p[65]));
}

// ---------------------------------------------------------------------------
// Fused: bilinear 8x upsample of skernel (4,9,32,32), per-pixel softmax,
// 3x3 reflect-padded apply to x. Grid (16, 256): x = n*4+cg, y = row h.
// ---------------------------------------------------------------------------
__global__ __launch_bounds__(256) void apply_fused(const float* __restrict__ x,
                                                   const float* __restrict__ sk,
                                                   float* __restrict__ out)
{
    __shared__ float skr[9][2][32];
    __shared__ float kvs[256 * 9];   // [w][9]
    const int bx = blockIdx.x;
    const int n  = bx >> 2;
    const int cg = bx & 3;
    const int h  = blockIdx.y;
    const int t  = threadIdx.x;

    float fs = (float)h * 31.0f / 255.0f;
    int r0 = (int)fs;
    float fh = fs - (float)r0;
    int r1 = min(r0 + 1, 31);

    for (int i = t; i < 576; i += 256) {
        int p = i >> 6, rsel = (i >> 5) & 1, c = i & 31;
        int rr = rsel ? r1 : r0;
        skr[p][rsel][c] = sk[((n * 9 + p) * 32 + rr) * 32 + c];
    }
    __syncthreads();

    {
        float fcs = (float)t * 31.0f / 255.0f;
        int c0 = (int)fcs;
        float fx = fcs - (float)c0;
        int c1 = min(c0 + 1, 31);
        float kv[9];
        float mx = -1e30f;
#pragma unroll
        for (int p = 0; p < 9; ++p) {
            float v0 = skr[p][0][c0] * (1.f - fx) + skr[p][0][c1] * fx;
            float v1 = skr[p][1][c0] * (1.f - fx) + skr[p][1][c1] * fx;
            float v  = v0 * (1.f - fh) + v1 * fh;
            kv[p] = v;
            mx = fmaxf(mx, v);
        }
        float ss = 0.f;
#pragma unroll
        for (int p = 0; p < 9; ++p) { kv[p] = __expf(kv[p] - mx); ss += kv[p]; }
        float inv = 1.f / ss;
#pragma unroll
        for (int p = 0; p < 9; ++p) kvs[t * 9 + p] = kv[p] * inv;
    }
    __syncthreads();

    const int wq = t & 63;
    const int cl = t >> 6;
    const int w4 = wq * 4;

    float kv[4][9];
#pragma unroll
    for (int j = 0; j < 4; ++j)
#pragma unroll
        for (int p = 0; p < 9; ++p) kv[j][p] = kvs[(w4 + j) * 9 + p];

    const int hm  = (h == 0) ? 1 : h - 1;
    const int hp  = (h == 255) ? 254 : h + 1;
    const int xle = (w4 == 0) ? 1 : w4 - 1;
    const int xre = (w4 == 252) ? 254 : w4 + 4;

    const int c0ch = cg * 12 + cl * 3;
    const float* xb = x + ((size_t)n * HIDC + c0ch) * 65536;
    float* ob = out + ((size_t)n * HIDC + c0ch) * 65536;

    for (int c = 0; c < 3; ++c) {
        const float* xp = xb + (size_t)c * 65536;
        const float* rm = xp + hm * 256;
        const float* rc = xp + h * 256;
        const float* rp = xp + hp * 256;
        float4 fm = *(const float4*)(rm + w4);
        float4 fc = *(const float4*)(rc + w4);
        float4 fp = *(const float4*)(rp + w4);
        float vm[6] = { rm[xle], fm.x, fm.y, fm.z, fm.w, rm[xre] };
        float vc[6] = { rc[xle], fc.x, fc.y, fc.z, fc.w, rc[xre] };
        float vp[6] = { rp[xle], fp.x, fp.y, fp.z, fp.w, rp[xre] };
        float4 o;
        float* op = &o.x;
#pragma unroll
        for (int j = 0; j < 4; ++j) {
            op[j] = kv[j][0] * vm[j] + kv[j][1] * vm[j + 1] + kv[j][2] * vm[j + 2]
                  + kv[j][3] * vc[j] + kv[j][4] * vc[j + 1] + kv[j][5] * vc[j + 2]
                  + kv[j][6] * vp[j] + kv[j][7] * vp[j + 1] + kv[j][8] * vp[j + 2];
        }
        *(float4*)(ob + (size_t)c * 65536 + h * 256 + w4) = o;
    }
}

extern "C" void kernel_launch(void* const* d_in, const int* in_sizes, int n_in,
                              void* d_out, int out_size, void* d_ws, size_t ws_size,
                              hipStream_t stream)
{
    const float* x       = (const float*)d_in[0];
    const float* x_      = (const float*)d_in[1];
    const float* pre1_w  = (const float*)d_in[2];
    const float* pre1_b  = (const float*)d_in[3];
    const float* pre1_a  = (const float*)d_in[4];
    const float* pre2_w  = (const float*)d_in[5];
    const float* pre2_b  = (const float*)d_in[6];
    const float* pre2_a  = (const float*)d_in[7];
    const float* prek_w1 = (const float*)d_in[8];
    const float* prek_b1 = (const float*)d_in[9];
    const float* prek_a  = (const float*)d_in[10];
    const float* prek_w2 = (const float*)d_in[11];
    const float* prek_b2 = (const float*)d_in[12];
    float* out = (float*)d_out;

    float* A   = (float*)d_ws;          // (4,48,64,64) = 786432
    float* B   = A + 786432;            // (4,48,64,64)
    float* RAW = B + 786432;            // (4,48,64,64) raw conv out
    float* C   = A;                     // (4,48,32,32) = 196608  (A dead by then)
    float* D   = A + 196608;            // (4,48,32,32)
    float* R2  = A + 393216;            // (4,48,32,32) raw conv out
    float* SK  = A + 589824;            // (4,9,32,32)

    const int W1 = 48 * 48 * 9;

    downsample4<<<3072, 256, 0, stream>>>(x_, A);

    // ---- 3 basic blocks @ 64x64 : 2px x 2co per thread, 768 blocks ----
    conv_tile<64, 64, 8, 2, 2, 2><<<dim3(24, 8, 4), 256, 0, stream>>>(A, pre1_w, pre1_b, RAW);
    norm_block<4096, 0><<<dim3(48, 4), 1024, 0, stream>>>(RAW, A, pre1_a, B);
    conv_tile<64, 64, 8, 2, 2, 2><<<dim3(24, 8, 4), 256, 0, stream>>>(B, pre1_w + W1, pre1_b + 48, RAW);
    norm_block<4096, 0><<<dim3(48, 4), 1024, 0, stream>>>(RAW, B, pre1_a + 1, A);
    conv_tile<64, 64, 8, 2, 2, 2><<<dim3(24, 8, 4), 256, 0, stream>>>(A, pre1_w + 2 * W1, pre1_b + 96, RAW);
    norm_block<4096, 0><<<dim3(48, 4), 1024, 0, stream>>>(RAW, A, pre1_a + 2, B);

    maxpool2k<<<768, 256, 0, stream>>>(B, C);

    // ---- 3 basic blocks @ 32x32 : 1px x 2co per thread, 384 blocks ----
    conv_tile<32, 32, 8, 2, 4, 1><<<dim3(24, 4, 4), 256, 0, stream>>>(C, pre2_w, pre2_b, R2);
    norm_block<1024, 0><<<dim3(48, 4), 1024, 0, stream>>>(R2, C, pre2_a, D);
    conv_tile<32, 32, 8, 2, 4, 1><<<dim3(24, 4, 4), 256, 0, stream>>>(D, pre2_w + W1, pre2_b + 48, R2);
    norm_block<1024, 0><<<dim3(48, 4), 1024, 0, stream>>>(R2, D, pre2_a + 1, C);
    conv_tile<32, 32, 8, 2, 4, 1><<<dim3(24, 4, 4), 256, 0, stream>>>(C, pre2_w + 2 * W1, pre2_b + 96, R2);
    norm_block<1024, 0><<<dim3(48, 4), 1024, 0, stream>>>(R2, C, pre2_a + 2, D);

    // ---- kernel-prediction heads ----
    conv_tile<32, 32, 8, 2, 4, 1><<<dim3(24, 4, 4), 256, 0, stream>>>(D, prek_w1, prek_b1, R2);
    norm_block<1024, 1><<<dim3(48, 4), 1024, 0, stream>>>(R2, nullptr, prek_a, C);
    conv_tile<32, 32, 8, 3, 4, 1><<<dim3(3, 4, 4), 256, 0, stream>>>(C, prek_w2, prek_b2, SK);

    apply_fused<<<dim3(16, 256), 256, 0, stream>>>(x, SK, out);
}